// Round 2
// baseline (72.598 us; speedup 1.0000x reference)
//
#include <hip/hip_runtime.h>

// INT8QuantizedLinear: B=16, S=512, IN=1024, OUT=4096
// M = 8192 tokens, N = 4096, K = 1024.
// NOTE: harness passes integer inputs widened to int32 -> weight arrives as
// const int* (one int32 per int8 value). We repack to true int8 in d_ws.

#define M_TOT 8192
#define N_TOT 4096
#define K_TOT 1024
#define QMAXF 127.0f

#define BM 128
#define BN 128
#define BKB 128   // K-bytes (=i8 elems) staged per LDS tile

typedef int i32x4 __attribute__((ext_vector_type(4)));

// ---------------------------------------------------------------------------
// Kernel 0: repack weights int32 -> int8 (harness widens integer inputs)
// ---------------------------------------------------------------------------
__global__ __launch_bounds__(256) void pack_w(const int* __restrict__ w32,
                                              signed char* __restrict__ w8) {
  const int i = blockIdx.x * 256 + threadIdx.x;  // one int4 (4 weights) per thread
  const int4 v = reinterpret_cast<const int4*>(w32)[i];
  const int packed = (v.x & 0xFF) | ((v.y & 0xFF) << 8) |
                     ((v.z & 0xFF) << 16) | (v.w << 24);
  reinterpret_cast<int*>(w8)[i] = packed;
}

// ---------------------------------------------------------------------------
// Kernel 1: per-token absmax quantization  x[f32, M x K] -> xq[i8], iscale[f32]
// ---------------------------------------------------------------------------
__global__ __launch_bounds__(256) void quant_rows(const float* __restrict__ x,
                                                  signed char* __restrict__ xq,
                                                  float* __restrict__ iscale) {
  const int token = blockIdx.x;
  const int t = threadIdx.x;

  const float4 v = reinterpret_cast<const float4*>(x)[(size_t)token * 256 + t];
  float m = fmaxf(fmaxf(fabsf(v.x), fabsf(v.y)), fmaxf(fabsf(v.z), fabsf(v.w)));

#pragma unroll
  for (int off = 32; off >= 1; off >>= 1) m = fmaxf(m, __shfl_xor(m, off, 64));

  __shared__ float wmax[4];
  const int lane = t & 63, wid = t >> 6;
  if (lane == 0) wmax[wid] = m;
  __syncthreads();
  const float amax = fmaxf(fmaxf(wmax[0], wmax[1]), fmaxf(wmax[2], wmax[3]));

  float scale = amax / QMAXF;
  if (scale == 0.0f) scale = 1.0f;

  int qi;
  signed char* qb = reinterpret_cast<signed char*>(&qi);
  qb[0] = (signed char)(int)fminf(fmaxf(rintf(v.x / scale), -128.0f), 127.0f);
  qb[1] = (signed char)(int)fminf(fmaxf(rintf(v.y / scale), -128.0f), 127.0f);
  qb[2] = (signed char)(int)fminf(fmaxf(rintf(v.z / scale), -128.0f), 127.0f);
  qb[3] = (signed char)(int)fminf(fmaxf(rintf(v.w / scale), -128.0f), 127.0f);
  reinterpret_cast<int*>(xq)[(size_t)token * 256 + t] = qi;

  if (t == 0) iscale[token] = scale;
}

// ---------------------------------------------------------------------------
// Kernel 2: i8 GEMM  out[M,N] = dequant( xq[M,K] * w8[N,K]^T )
// 128x128 tile, 4 waves (2x2), mfma_i32_16x16x64_i8, global_load_lds staging
// with pre-swizzled global source (col ^= (row&7)<<4) for conflict-free reads.
// ---------------------------------------------------------------------------
__device__ __forceinline__ void gload_lds16(const void* g, void* l) {
  __builtin_amdgcn_global_load_lds(
      (const __attribute__((address_space(1))) unsigned int*)g,
      (__attribute__((address_space(3))) unsigned int*)l, 16, 0, 0);
}

__global__ __launch_bounds__(256) void int8_gemm(const signed char* __restrict__ xq,
                                                 const signed char* __restrict__ w,
                                                 const float* __restrict__ iscale,
                                                 const float* __restrict__ wscale,
                                                 const float* __restrict__ bias,
                                                 float* __restrict__ out) {
  __shared__ __attribute__((aligned(16))) signed char As[BM * BKB];
  __shared__ __attribute__((aligned(16))) signed char Bs[BN * BKB];

  const int t = threadIdx.x;
  const int lane = t & 63;
  const int wid = t >> 6;   // 0..3
  const int wm = wid >> 1;  // 0..1 (wave row)
  const int wn = wid & 1;   // 0..1 (wave col)

  const int m0 = blockIdx.y * BM;
  const int n0 = blockIdx.x * BN;

  // staging decomposition: each call = 256 thr x 16B = 32 rows of 128B
  const int srow = t >> 3;                                  // 0..31
  const int scol_swz = ((t & 7) * 16) ^ ((srow & 7) << 4);  // pre-swizzled source col

  i32x4 acc[4][4] = {};

  for (int kt = 0; kt < K_TOT / BKB; ++kt) {
    const int k0 = kt * BKB;
#pragma unroll
    for (int c = 0; c < 4; ++c) {
      const int row = c * 32 + srow;
      gload_lds16(xq + (size_t)(m0 + row) * K_TOT + k0 + scol_swz,
                  &As[c * 4096 + t * 16]);
      gload_lds16(w + (size_t)(n0 + row) * K_TOT + k0 + scol_swz,
                  &Bs[c * 4096 + t * 16]);
    }
    __syncthreads();  // drains vmcnt(0): staged tiles visible

#pragma unroll
    for (int kk = 0; kk < 2; ++kk) {
      const int kofs = kk * 64 + ((lane >> 4) * 16);  // 16B k-slice for this lane group
      i32x4 a[4], b[4];
#pragma unroll
      for (int f = 0; f < 4; ++f) {
        const int ar = wm * 64 + f * 16 + (lane & 15);
        a[f] = *reinterpret_cast<const i32x4*>(&As[ar * BKB + (kofs ^ ((ar & 7) << 4))]);
        const int br = wn * 64 + f * 16 + (lane & 15);
        b[f] = *reinterpret_cast<const i32x4*>(&Bs[br * BKB + (kofs ^ ((br & 7) << 4))]);
      }
#pragma unroll
      for (int fm = 0; fm < 4; ++fm)
#pragma unroll
        for (int fn = 0; fn < 4; ++fn)
          acc[fm][fn] = __builtin_amdgcn_mfma_i32_16x16x64_i8(a[fm], b[fn], acc[fm][fn], 0, 0, 0);
    }
    __syncthreads();  // all LDS reads done before next stage overwrites
  }

  // Epilogue: C/D layout col=lane&15, row=(lane>>4)*4+i (guide §3, dtype-independent)
  const int col = lane & 15;
  const int rq = lane >> 4;
#pragma unroll
  for (int fn = 0; fn < 4; ++fn) {
    const int gn = n0 + wn * 64 + fn * 16 + col;
    const float wsc = wscale[gn];
    const float bv = bias[gn];
#pragma unroll
    for (int fm = 0; fm < 4; ++fm) {
      const int gm0 = m0 + wm * 64 + fm * 16 + rq * 4;
#pragma unroll
      for (int i = 0; i < 4; ++i) {
        const int gm = gm0 + i;
        const float isc = iscale[gm];
        out[(size_t)gm * N_TOT + gn] = ((float)acc[fm][fn][i] * wsc) * isc + bv;
      }
    }
  }
}

// ---------------------------------------------------------------------------
extern "C" void kernel_launch(void* const* d_in, const int* in_sizes, int n_in,
                              void* d_out, int out_size, void* d_ws, size_t ws_size,
                              hipStream_t stream) {
  const float* x = (const float*)d_in[0];
  const int* w32 = (const int*)d_in[1];     // harness widens int8 -> int32
  const float* wscale = (const float*)d_in[2];
  const float* bias = (const float*)d_in[3];
  float* out = (float*)d_out;

  // workspace layout: xq (M*K i8 = 8MB) | iscale (M f32 = 32KB) | w8 (N*K i8 = 4MB)
  signed char* xq = (signed char*)d_ws;
  float* iscale = (float*)((char*)d_ws + (size_t)M_TOT * K_TOT);
  signed char* w8 = (signed char*)((char*)d_ws + (size_t)M_TOT * K_TOT + M_TOT * 4);

  pack_w<<<(N_TOT * K_TOT / 4) / 256, 256, 0, stream>>>(w32, w8);
  quant_rows<<<M_TOT, 256, 0, stream>>>(x, xq, iscale);
  int8_gemm<<<dim3(N_TOT / BN, M_TOT / BM), 256, 0, stream>>>(xq, w8, iscale, wscale, bias, out);
}

// Round 3
// 63.934 us; speedup vs baseline: 1.1355x; 1.1355x over previous
//
#include <hip/hip_runtime.h>

// INT8QuantizedLinear: B=16, S=512, IN=1024, OUT=4096
// M = 8192 tokens, N = 4096, K = 1024.
// Harness widens integer inputs: weight arrives as const int* (int32 per value).
// Round 3: 256x256 tile, 8-wave, double-buffered LDS (128 KiB), prefetch-before-
// compute 2-phase pipeline (T3 minimum recipe), XCD swizzle, fused prep kernel.

#define M_TOT 8192
#define N_TOT 4096
#define K_TOT 1024
#define QMAXF 127.0f

#define BM 256
#define BN 256
#define BK 128              // K-bytes (= i8 elems) per LDS K-tile
#define NKT (K_TOT / BK)    // 8 K-tiles

typedef int i32x4 __attribute__((ext_vector_type(4)));

// ---------------------------------------------------------------------------
// Kernel 0: fused prep.
//   blocks [0, 8192):      per-token absmax quant  x[f32] -> xq[i8], iscale
//   blocks [8192, 12288):  weight repack int32 -> int8
// ---------------------------------------------------------------------------
__global__ __launch_bounds__(256) void prep(const float* __restrict__ x,
                                            const int* __restrict__ w32,
                                            signed char* __restrict__ xq,
                                            signed char* __restrict__ w8,
                                            float* __restrict__ iscale) {
  const int b = blockIdx.x;
  const int t = threadIdx.x;

  if (b < M_TOT) {  // ---- quantization: one token per block ----
    const float4 v = reinterpret_cast<const float4*>(x)[(size_t)b * 256 + t];
    float m = fmaxf(fmaxf(fabsf(v.x), fabsf(v.y)), fmaxf(fabsf(v.z), fabsf(v.w)));
#pragma unroll
    for (int off = 32; off >= 1; off >>= 1) m = fmaxf(m, __shfl_xor(m, off, 64));

    __shared__ float wmax[4];
    const int lane = t & 63, wid = t >> 6;
    if (lane == 0) wmax[wid] = m;
    __syncthreads();
    const float amax = fmaxf(fmaxf(wmax[0], wmax[1]), fmaxf(wmax[2], wmax[3]));

    float scale = amax / QMAXF;
    if (scale == 0.0f) scale = 1.0f;

    int qi;
    signed char* qb = reinterpret_cast<signed char*>(&qi);
    qb[0] = (signed char)(int)fminf(fmaxf(rintf(v.x / scale), -128.0f), 127.0f);
    qb[1] = (signed char)(int)fminf(fmaxf(rintf(v.y / scale), -128.0f), 127.0f);
    qb[2] = (signed char)(int)fminf(fmaxf(rintf(v.z / scale), -128.0f), 127.0f);
    qb[3] = (signed char)(int)fminf(fmaxf(rintf(v.w / scale), -128.0f), 127.0f);
    reinterpret_cast<int*>(xq)[(size_t)b * 256 + t] = qi;

    if (t == 0) iscale[b] = scale;
  } else {  // ---- weight repack: 4 weights per thread ----
    const int i = (b - M_TOT) * 256 + t;
    const int4 v = reinterpret_cast<const int4*>(w32)[i];
    const int packed = (v.x & 0xFF) | ((v.y & 0xFF) << 8) |
                       ((v.z & 0xFF) << 16) | (v.w << 24);
    reinterpret_cast<int*>(w8)[i] = packed;
  }
}

// ---------------------------------------------------------------------------
// Kernel 1: i8 GEMM  out[M,N] = dequant( xq[M,K] * w8[N,K]^T )
// 256x256 tile, 8 waves (2x4), mfma_i32_16x16x64_i8, double-buffered LDS,
// prefetch(next K-tile) issued before MFMA(current) so the single per-tile
// __syncthreads (vmcnt(0)+lgkmcnt(0) drain) lands after compute hid latency.
// XOR-swizzle (byte ^= (row&7)<<4) on both stage-source and ds_read (G21).
// ---------------------------------------------------------------------------
__device__ __forceinline__ void gload_lds16(const void* g, void* l) {
  __builtin_amdgcn_global_load_lds(
      (const __attribute__((address_space(1))) unsigned int*)g,
      (__attribute__((address_space(3))) unsigned int*)l, 16, 0, 0);
}

__global__ __launch_bounds__(512, 2) void int8_gemm(const signed char* __restrict__ xq,
                                                    const signed char* __restrict__ w,
                                                    const float* __restrict__ iscale,
                                                    const float* __restrict__ wscale,
                                                    const float* __restrict__ bias,
                                                    float* __restrict__ out) {
  __shared__ __attribute__((aligned(16))) signed char As[2][BM][BK];  // 64 KiB
  __shared__ __attribute__((aligned(16))) signed char Bs[2][BN][BK];  // 64 KiB

  const int t = threadIdx.x;
  const int lane = t & 63;
  const int wid = t >> 6;   // 0..7
  const int wm = wid >> 2;  // 0..1 -> wave rows (128 each)
  const int wn = wid & 3;   // 0..3 -> wave cols (64 each)

  // XCD-aware swizzle: 512 blocks, 8 XCDs, 64 contiguous per XCD (512%8==0)
  const int bid = blockIdx.x;
  const int swz = (bid & 7) * 64 + (bid >> 3);
  const int m0 = (swz >> 4) * BM;  // 32 m-blocks
  const int n0 = (swz & 15) * BN;  // 16 n-blocks

  // staging: one pass = 512 thr x 16 B = 64 rows of 128 B
  const int srow = t >> 3;                                  // 0..63
  const int scol_swz = ((t & 7) * 16) ^ ((srow & 7) << 4);  // pre-swizzled source

  auto stage = [&](int buf, int kt) {
    const int k0 = kt * BK;
#pragma unroll
    for (int c = 0; c < 4; ++c) {
      gload_lds16(xq + (size_t)(m0 + c * 64 + srow) * K_TOT + k0 + scol_swz,
                  &As[buf][c * 64][0] + t * 16);
      gload_lds16(w + (size_t)(n0 + c * 64 + srow) * K_TOT + k0 + scol_swz,
                  &Bs[buf][c * 64][0] + t * 16);
    }
  };

  i32x4 acc[8][4] = {};

  stage(0, 0);
  __syncthreads();  // drain prologue stage

  for (int kt = 0; kt < NKT; ++kt) {
    const int cur = kt & 1;
    if (kt + 1 < NKT) stage(cur ^ 1, kt + 1);  // issue next-tile loads first

#pragma unroll
    for (int ks = 0; ks < 2; ++ks) {
      const int kofs = ks * 64 + ((lane >> 4) * 16);
      i32x4 a[8], b[4];
#pragma unroll
      for (int f = 0; f < 8; ++f) {
        const int r = wm * 128 + f * 16 + (lane & 15);
        a[f] = *reinterpret_cast<const i32x4*>(&As[cur][r][kofs ^ ((r & 7) << 4)]);
      }
#pragma unroll
      for (int g = 0; g < 4; ++g) {
        const int r = wn * 64 + g * 16 + (lane & 15);
        b[g] = *reinterpret_cast<const i32x4*>(&Bs[cur][r][kofs ^ ((r & 7) << 4)]);
      }
#pragma unroll
      for (int f = 0; f < 8; ++f)
#pragma unroll
        for (int g = 0; g < 4; ++g)
          acc[f][g] = __builtin_amdgcn_mfma_i32_16x16x64_i8(a[f], b[g], acc[f][g], 0, 0, 0);
    }
    __syncthreads();  // single per-tile drain: next tile landed, reads done
  }

  // Epilogue: C/D layout col=lane&15, row=(lane>>4)*4+i (validated round 2)
  const int col = lane & 15;
  const int rq = lane >> 4;
  float wsc[4], bv[4];
#pragma unroll
  for (int g = 0; g < 4; ++g) {
    const int gn = n0 + wn * 64 + g * 16 + col;
    wsc[g] = wscale[gn];
    bv[g] = bias[gn];
  }
#pragma unroll
  for (int f = 0; f < 8; ++f) {
    const int gmb = m0 + wm * 128 + f * 16 + rq * 4;
#pragma unroll
    for (int i = 0; i < 4; ++i) {
      const int gm = gmb + i;
      const float isc = iscale[gm];
      float* rowp = out + (size_t)gm * N_TOT + n0 + wn * 64 + col;
#pragma unroll
      for (int g = 0; g < 4; ++g)
        rowp[g * 16] = (float)acc[f][g][i] * wsc[g] * isc + bv[g];
    }
  }
}

// ---------------------------------------------------------------------------
extern "C" void kernel_launch(void* const* d_in, const int* in_sizes, int n_in,
                              void* d_out, int out_size, void* d_ws, size_t ws_size,
                              hipStream_t stream) {
  const float* x = (const float*)d_in[0];
  const int* w32 = (const int*)d_in[1];  // harness widens int8 -> int32
  const float* wscale = (const float*)d_in[2];
  const float* bias = (const float*)d_in[3];
  float* out = (float*)d_out;

  // workspace: xq (8 MB) | iscale (32 KB) | w8 (4 MB)
  signed char* xq = (signed char*)d_ws;
  float* iscale = (float*)((char*)d_ws + (size_t)M_TOT * K_TOT);
  signed char* w8 = (signed char*)((char*)d_ws + (size_t)M_TOT * K_TOT + M_TOT * 4);

  const int pack_blocks = (N_TOT * K_TOT / 4) / 256;  // 4096
  prep<<<M_TOT + pack_blocks, 256, 0, stream>>>(x, w32, xq, w8, iscale);
  int8_gemm<<<dim3((M_TOT / BM) * (N_TOT / BN)), 512, 0, stream>>>(xq, w8, iscale, wscale, bias, out);
}

// Round 4
// 63.509 us; speedup vs baseline: 1.1431x; 1.0067x over previous
//
#include <hip/hip_runtime.h>

// INT8QuantizedLinear: B=16, S=512, IN=1024, OUT=4096  (M=8192, N=4096, K=1024)
// Harness widens integer inputs: weight arrives as const int* (int32 per value).
// Round 4: 256x256 tile, 8-wave, double-buffered LDS, 3-phase counted-vmcnt
// pipeline (T3+T4), raw s_barrier (no vmcnt(0) drain in main loop), T5 setprio.
// Race-freedom by construction:
//   alpha stages B(U+1) -> buf^1 B  (alpha reads buf A/B ks0: disjoint buffer)
//   delta stages A(U+2) -> buf   A  (delta does NO LDS reads; A last read in
//                                    gamma, sealed by delta's barrier)
//   vmcnt(4): only slot newer than the needed B(U) is A(U+1) (4 loads).

#define M_TOT 8192
#define N_TOT 4096
#define K_TOT 1024
#define QMAXF 127.0f

#define BM 256
#define BN 256
#define BK 128              // i8 elems per LDS K-tile (128 B rows)
#define NKT (K_TOT / BK)    // 8

typedef int i32x4 __attribute__((ext_vector_type(4)));

// ---------------------------------------------------------------------------
// Kernel 0: fused prep (quant blocks [0,8192), weight repack [8192,12288))
// ---------------------------------------------------------------------------
__global__ __launch_bounds__(256) void prep(const float* __restrict__ x,
                                            const int* __restrict__ w32,
                                            signed char* __restrict__ xq,
                                            signed char* __restrict__ w8,
                                            float* __restrict__ iscale) {
  const int b = blockIdx.x;
  const int t = threadIdx.x;

  if (b < M_TOT) {
    const float4 v = reinterpret_cast<const float4*>(x)[(size_t)b * 256 + t];
    float m = fmaxf(fmaxf(fabsf(v.x), fabsf(v.y)), fmaxf(fabsf(v.z), fabsf(v.w)));
#pragma unroll
    for (int off = 32; off >= 1; off >>= 1) m = fmaxf(m, __shfl_xor(m, off, 64));

    __shared__ float wmax[4];
    const int lane = t & 63, wid = t >> 6;
    if (lane == 0) wmax[wid] = m;
    __syncthreads();
    const float amax = fmaxf(fmaxf(wmax[0], wmax[1]), fmaxf(wmax[2], wmax[3]));

    float scale = amax / QMAXF;
    if (scale == 0.0f) scale = 1.0f;

    int qi;
    signed char* qb = reinterpret_cast<signed char*>(&qi);
    qb[0] = (signed char)(int)fminf(fmaxf(rintf(v.x / scale), -128.0f), 127.0f);
    qb[1] = (signed char)(int)fminf(fmaxf(rintf(v.y / scale), -128.0f), 127.0f);
    qb[2] = (signed char)(int)fminf(fmaxf(rintf(v.z / scale), -128.0f), 127.0f);
    qb[3] = (signed char)(int)fminf(fmaxf(rintf(v.w / scale), -128.0f), 127.0f);
    reinterpret_cast<int*>(xq)[(size_t)b * 256 + t] = qi;

    if (t == 0) iscale[b] = scale;
  } else {
    const int i = (b - M_TOT) * 256 + t;
    const int4 v = reinterpret_cast<const int4*>(w32)[i];
    const int packed = (v.x & 0xFF) | ((v.y & 0xFF) << 8) |
                       ((v.z & 0xFF) << 16) | (v.w << 24);
    reinterpret_cast<int*>(w8)[i] = packed;
  }
}

// ---------------------------------------------------------------------------
__device__ __forceinline__ void gload_lds16(const void* g, void* l) {
  __builtin_amdgcn_global_load_lds(
      (const __attribute__((address_space(1))) unsigned int*)g,
      (__attribute__((address_space(3))) unsigned int*)l, 16, 0, 0);
}

__global__ __launch_bounds__(512, 2) void int8_gemm(const signed char* __restrict__ xq,
                                                    const signed char* __restrict__ w,
                                                    const float* __restrict__ iscale,
                                                    const float* __restrict__ wscale,
                                                    const float* __restrict__ bias,
                                                    float* __restrict__ out) {
  __shared__ __attribute__((aligned(16))) signed char As[2][BM][BK];  // 64 KiB
  __shared__ __attribute__((aligned(16))) signed char Bs[2][BN][BK];  // 64 KiB

  const int t = threadIdx.x;
  const int lane = t & 63;
  const int wid = t >> 6;   // 0..7
  const int wm = wid >> 2;  // 0..1 (128-row half)
  const int wn = wid & 3;   // 0..3 (64-col quarter)

  // XCD-aware swizzle: 512 blocks, 8 XCDs, 64 contiguous per XCD
  const int bid = blockIdx.x;
  const int swz = (bid & 7) * 64 + (bid >> 3);
  const int m0 = (swz >> 4) * BM;
  const int n0 = (swz & 15) * BN;

  // staging: one pass = 512 thr x 16 B = 64 rows of 128 B; linear LDS dest,
  // pre-swizzled global source (involution byte^((row&7)<<4))
  const int srow = t >> 3;
  const int scol_swz = ((t & 7) * 16) ^ ((srow & 7) << 4);

  auto stageA = [&](int buf, int kt) {
    const int k0 = kt * BK;
#pragma unroll
    for (int c = 0; c < 4; ++c)
      gload_lds16(xq + (size_t)(m0 + c * 64 + srow) * K_TOT + k0 + scol_swz,
                  &As[buf][c * 64][0] + t * 16);
  };
  auto stageB = [&](int buf, int kt) {
    const int k0 = kt * BK;
#pragma unroll
    for (int c = 0; c < 4; ++c)
      gload_lds16(w + (size_t)(n0 + c * 64 + srow) * K_TOT + k0 + scol_swz,
                  &Bs[buf][c * 64][0] + t * 16);
  };

  const int kql = (lane >> 4) * 16;  // 16B k-subslice within a 64B k-half

  i32x4 acc[8][4] = {};

  // prologue: A(0), B(0), A(1)  (12 loads in flight)
  stageA(0, 0);
  stageB(0, 0);
  stageA(1, 1);

  for (int U = 0; U < NKT - 1; ++U) {
    const int cur = U & 1;

    // ---- phase alpha: ks0, all 4 n-frags ----
    asm volatile("s_waitcnt vmcnt(4)\n\ts_barrier" ::: "memory");
    stageB(cur ^ 1, U + 1);

    i32x4 a0[8], b0[4];
#pragma unroll
    for (int f = 0; f < 8; ++f) {
      const int r = wm * 128 + f * 16 + (lane & 15);
      a0[f] = *reinterpret_cast<const i32x4*>(&As[cur][r][kql ^ ((r & 7) << 4)]);
    }
#pragma unroll
    for (int g = 0; g < 4; ++g) {
      const int r = wn * 64 + g * 16 + (lane & 15);
      b0[g] = *reinterpret_cast<const i32x4*>(&Bs[cur][r][kql ^ ((r & 7) << 4)]);
    }
    __builtin_amdgcn_s_setprio(1);
#pragma unroll
    for (int f = 0; f < 8; ++f)
#pragma unroll
      for (int g = 0; g < 4; ++g)
        acc[f][g] = __builtin_amdgcn_mfma_i32_16x16x64_i8(a0[f], b0[g], acc[f][g], 0, 0, 0);
    __builtin_amdgcn_s_setprio(0);

    // ---- phase gamma: ks1, n-frags 0,1 ----
    asm volatile("s_barrier" ::: "memory");
    i32x4 a1[8], b1[4];
#pragma unroll
    for (int f = 0; f < 8; ++f) {
      const int r = wm * 128 + f * 16 + (lane & 15);
      a1[f] = *reinterpret_cast<const i32x4*>(&As[cur][r][(64 + kql) ^ ((r & 7) << 4)]);
    }
#pragma unroll
    for (int g = 0; g < 4; ++g) {
      const int r = wn * 64 + g * 16 + (lane & 15);
      b1[g] = *reinterpret_cast<const i32x4*>(&Bs[cur][r][(64 + kql) ^ ((r & 7) << 4)]);
    }
    __builtin_amdgcn_s_setprio(1);
#pragma unroll
    for (int f = 0; f < 8; ++f)
#pragma unroll
      for (int g = 0; g < 2; ++g)
        acc[f][g] = __builtin_amdgcn_mfma_i32_16x16x64_i8(a1[f], b1[g], acc[f][g], 0, 0, 0);
    __builtin_amdgcn_s_setprio(0);

    // ---- phase delta: ks1, n-frags 2,3 (registers only) + stage A(U+2) ----
    asm volatile("s_barrier" ::: "memory");
    if (U + 2 < NKT) stageA(cur, U + 2);
    __builtin_amdgcn_s_setprio(1);
#pragma unroll
    for (int f = 0; f < 8; ++f)
#pragma unroll
      for (int g = 2; g < 4; ++g)
        acc[f][g] = __builtin_amdgcn_mfma_i32_16x16x64_i8(a1[f], b1[g], acc[f][g], 0, 0, 0);
    __builtin_amdgcn_s_setprio(0);
  }

  // ---- peeled last tile U = NKT-1 (no stages; drain) ----
  {
    const int cur = (NKT - 1) & 1;
    asm volatile("s_waitcnt vmcnt(0)\n\ts_barrier" ::: "memory");
    i32x4 a0[8], b0[4];
#pragma unroll
    for (int ks = 0; ks < 2; ++ks) {
      const int kofs = ks * 64 + kql;
#pragma unroll
      for (int f = 0; f < 8; ++f) {
        const int r = wm * 128 + f * 16 + (lane & 15);
        a0[f] = *reinterpret_cast<const i32x4*>(&As[cur][r][kofs ^ ((r & 7) << 4)]);
      }
#pragma unroll
      for (int g = 0; g < 4; ++g) {
        const int r = wn * 64 + g * 16 + (lane & 15);
        b0[g] = *reinterpret_cast<const i32x4*>(&Bs[cur][r][kofs ^ ((r & 7) << 4)]);
      }
#pragma unroll
      for (int f = 0; f < 8; ++f)
#pragma unroll
        for (int g = 0; g < 4; ++g)
          acc[f][g] = __builtin_amdgcn_mfma_i32_16x16x64_i8(a0[f], b0[g], acc[f][g], 0, 0, 0);
    }
  }

  // ---- epilogue (validated rounds 2-3): col=lane&15, row=(lane>>4)*4+i ----
  const int col = lane & 15;
  const int rq = lane >> 4;
  float wsc[4], bv[4];
#pragma unroll
  for (int g = 0; g < 4; ++g) {
    const int gn = n0 + wn * 64 + g * 16 + col;
    wsc[g] = wscale[gn];
    bv[g] = bias[gn];
  }
#pragma unroll
  for (int f = 0; f < 8; ++f) {
    const int gmb = m0 + wm * 128 + f * 16 + rq * 4;
#pragma unroll
    for (int i = 0; i < 4; ++i) {
      const int gm = gmb + i;
      const float isc = iscale[gm];
      float* rowp = out + (size_t)gm * N_TOT + n0 + wn * 64 + col;
#pragma unroll
      for (int g = 0; g < 4; ++g)
        rowp[g * 16] = (float)acc[f][g][i] * wsc[g] * isc + bv[g];
    }
  }
}

// ---------------------------------------------------------------------------
extern "C" void kernel_launch(void* const* d_in, const int* in_sizes, int n_in,
                              void* d_out, int out_size, void* d_ws, size_t ws_size,
                              hipStream_t stream) {
  const float* x = (const float*)d_in[0];
  const int* w32 = (const int*)d_in[1];
  const float* wscale = (const float*)d_in[2];
  const float* bias = (const float*)d_in[3];
  float* out = (float*)d_out;

  signed char* xq = (signed char*)d_ws;                                    // 8 MB
  float* iscale = (float*)((char*)d_ws + (size_t)M_TOT * K_TOT);           // 32 KB
  signed char* w8 = (signed char*)((char*)d_ws + (size_t)M_TOT * K_TOT + M_TOT * 4);  // 4 MB

  const int pack_blocks = (N_TOT * K_TOT / 4) / 256;
  prep<<<M_TOT + pack_blocks, 256, 0, stream>>>(x, w32, xq, w8, iscale);
  int8_gemm<<<dim3((M_TOT / BM) * (N_TOT / BN)), 512, 0, stream>>>(xq, w8, iscale, wscale, bias, out);
}